// Round 7
// baseline (621.989 us; speedup 1.0000x reference)
//
#include <hip/hip_runtime.h>
#include <hip/hip_bf16.h>
#include <stdint.h>

// Fused: C = GroupNorm(mish(hardtanh(x @ W^T + b_lin + b_ext))) * gw + gb
// R6: 256x256 tile, BK=64, 8 waves, double-buffered LDS with COUNTED vmcnt(8)
// across raw s_barriers (no drain) + XOR-involution LDS layout (proven 0-conflict
// in R3-R6) + setprio around MFMA cluster. GN fused: 2 groups per tile.

constexpr int Mdim = 8192;
constexpr int Ndim = 4096;
constexpr int Kdim = 4096;
constexpr int BM = 256, BN = 256, BK = 64;
constexpr int NT = Kdim / BK;  // 64
constexpr float GN_EPS_F = 1e-5f;

typedef __bf16 bf16x8 __attribute__((ext_vector_type(8)));
typedef float f32x4 __attribute__((ext_vector_type(4)));

__device__ __forceinline__ unsigned short bf16_rne(float f) {
  unsigned int u = __float_as_uint(f);
  u += 0x7FFFu + ((u >> 16) & 1u);
  return (unsigned short)(u >> 16);
}

__global__ __launch_bounds__(256) void cvt_x(const float* __restrict__ in,
                                             unsigned short* __restrict__ out, int n4) {
  int idx = blockIdx.x * blockDim.x + threadIdx.x;
  int stride = gridDim.x * blockDim.x;
  const float4* in4 = reinterpret_cast<const float4*>(in);
  ushort4* out4 = reinterpret_cast<ushort4*>(out);
  for (int i = idx; i < n4; i += stride) {
    float4 f = in4[i];
    ushort4 o;
    o.x = bf16_rne(f.x); o.y = bf16_rne(f.y);
    o.z = bf16_rne(f.z); o.w = bf16_rne(f.w);
    out4[i] = o;
  }
}

__global__ __launch_bounds__(256) void cvt_w(const float* __restrict__ in,
                                             unsigned short* __restrict__ out, int n4) {
  int idx = blockIdx.x * blockDim.x + threadIdx.x;
  int stride = gridDim.x * blockDim.x;
  const float4* in4 = reinterpret_cast<const float4*>(in);
  ushort4* out4 = reinterpret_cast<ushort4*>(out);
  for (int i = idx; i < n4; i += stride) {
    float4 f = in4[i];
    ushort4 o;
    o.x = bf16_rne(f.x); o.y = bf16_rne(f.y);
    o.z = bf16_rne(f.z); o.w = bf16_rne(f.w);
    out4[i] = o;
  }
}

__device__ __forceinline__ void gload16(const void* g, void* l) {
  __builtin_amdgcn_global_load_lds((const __attribute__((address_space(1))) void*)g,
                                   (__attribute__((address_space(3))) void*)l,
                                   16, 0, 0);
}

#define WAITV(N) asm volatile("s_waitcnt vmcnt(" #N ")" ::: "memory")

__global__ __launch_bounds__(512, 2) void fused_gemm_gn(
    const unsigned short* __restrict__ Abf,   // x bf16 [M][K]
    const unsigned short* __restrict__ Bbf,   // W bf16 [N][K]
    const float* __restrict__ blin,
    const float* __restrict__ bext,
    const float* __restrict__ gnw,
    const float* __restrict__ gnb,
    float* __restrict__ out) {
  // LDS: 2 x (A 32KB + B 32KB) = 128 KB, + 8 KB GN reduction
  __shared__ __align__(16) unsigned short As[2][BM * BK];
  __shared__ __align__(16) unsigned short Bs[2][BN * BK];
  __shared__ float red[4][BM][2];  // [wn][block row][sum,sumsq]

  // bijective XCD swizzle: nwg = 512 = 8 * 64
  int bid = blockIdx.x;
  int swz = (bid & 7) * 64 + (bid >> 3);
  int bx = swz & 15;   // 16 N tiles
  int by = swz >> 4;   // 32 M tiles
  int row0 = by * BM;
  int col0 = bx * BN;

  int tid = threadIdx.x;
  int w = tid >> 6;        // wave 0..7
  int lane = tid & 63;
  int wm = w >> 2;         // 0/1 -> 128 M-rows
  int wn = w & 3;          // 0..3 -> 64 N-cols
  int l4 = lane >> 4;      // 0..3
  int lm = lane & 15;      // 0..15

  // staging: per matrix 2048 chunks of 16B; thread handles c = i*512+tid,
  // r = c>>3, j = (c&7)^(r&7)  (inverse of read-side XOR; LDS dest linear)
  int aoff[4], boff[4], lds8[4];
#pragma unroll
  for (int i = 0; i < 4; ++i) {
    int c = i * 512 + tid;
    int r = c >> 3;
    int j = (c & 7) ^ (r & 7);
    aoff[i] = (row0 + r) * Kdim + j * 8;
    boff[i] = (col0 + r) * Kdim + j * 8;
    lds8[i] = c * 8;  // ushort offset of chunk c
  }

  f32x4 acc[8][4] = {};

  // prologue: stage K-tile 0 into buf 0
#pragma unroll
  for (int i = 0; i < 4; ++i) {
    gload16(Abf + aoff[i], (void*)&As[0][lds8[i]]);
    gload16(Bbf + boff[i], (void*)&Bs[0][lds8[i]]);
  }

  for (int t = 0; t < NT; ++t) {
    int cur = t & 1;
    if (t + 1 < NT) {
      int kof = (t + 1) * BK;
#pragma unroll
      for (int i = 0; i < 4; ++i) {
        gload16(Abf + (aoff[i] + kof), (void*)&As[cur ^ 1][lds8[i]]);
        gload16(Bbf + (boff[i] + kof), (void*)&Bs[cur ^ 1][lds8[i]]);
      }
      WAITV(8);   // keep next tile's 8 loads in flight; this tile's are done
    } else {
      WAITV(0);   // final tile: drain
    }
    __builtin_amdgcn_s_barrier();        // staging of buf[cur] globally visible
    __builtin_amdgcn_sched_barrier(0);   // no hoisting of ds_reads above

    const bf16x8* Ap = reinterpret_cast<const bf16x8*>(As[cur]);
    const bf16x8* Bp = reinterpret_cast<const bf16x8*>(Bs[cur]);
    __builtin_amdgcn_s_setprio(1);
#pragma unroll
    for (int kk = 0; kk < 2; ++kk) {
      bf16x8 a[8], b[4];
#pragma unroll
      for (int m = 0; m < 8; ++m) {
        int r = wm * 128 + m * 16 + lm;
        a[m] = Ap[r * 8 + ((kk * 4 + l4) ^ (r & 7))];
      }
#pragma unroll
      for (int n = 0; n < 4; ++n) {
        int r = wn * 64 + n * 16 + lm;
        b[n] = Bp[r * 8 + ((kk * 4 + l4) ^ (r & 7))];
      }
#pragma unroll
      for (int m = 0; m < 8; ++m)
#pragma unroll
        for (int n = 0; n < 4; ++n)
          acc[m][n] = __builtin_amdgcn_mfma_f32_16x16x32_bf16(a[m], b[n], acc[m][n], 0, 0, 0);
    }
    __builtin_amdgcn_s_setprio(0);
    __builtin_amdgcn_s_barrier();        // all reads of buf[cur] done ->
    __builtin_amdgcn_sched_barrier(0);   // next iter may overwrite buf[cur^1... (t+2 path)
  }

  // ---- epilogue: biases, hardtanh, mish, groupnorm (2 groups of 128 per tile) ----
  float vbl[4], vbe[4], vgw[4], vgb[4];
#pragma unroll
  for (int n = 0; n < 4; ++n) {
    int c = col0 + wn * 64 + n * 16 + lm;
    vbl[n] = blin[c];
    vbe[n] = bext[c];
    vgw[n] = gnw[c];
    vgb[n] = gnb[c];
  }

  // activation + per-row partial sums over this wave's 64 cols
  // C/D frag layout: row = l4*4 + i, col = lm
#pragma unroll
  for (int m = 0; m < 8; ++m) {
#pragma unroll
    for (int i = 0; i < 4; ++i) {
      float s1 = 0.f, s2 = 0.f;
#pragma unroll
      for (int n = 0; n < 4; ++n) {
        float y = acc[m][n][i] + vbl[n] + vbe[n];
        y = fminf(fmaxf(y, -1.f), 1.f);
        float t = __expf(y);
        float num = t * t + 2.f * t;
        float mm = y * num / (num + 2.f);
        acc[m][n][i] = mm;
        s1 += mm;
        s2 += mm * mm;
      }
#pragma unroll
      for (int off = 1; off < 16; off <<= 1) {
        s1 += __shfl_xor(s1, off, 64);
        s2 += __shfl_xor(s2, off, 64);
      }
      if (lm == 0) {
        int r = wm * 128 + m * 16 + l4 * 4 + i;
        red[wn][r][0] = s1;
        red[wn][r][1] = s2;
      }
    }
  }
  __syncthreads();

  int h2 = (wn >> 1) << 1;  // 0 for group cols [0,128), 2 for [128,256)
#pragma unroll
  for (int m = 0; m < 8; ++m) {
#pragma unroll
    for (int i = 0; i < 4; ++i) {
      int r = wm * 128 + m * 16 + l4 * 4 + i;
      float s1 = red[h2][r][0] + red[h2 + 1][r][0];
      float s2 = red[h2][r][1] + red[h2 + 1][r][1];
      float mean = s1 * (1.f / 128.f);
      float var = s2 * (1.f / 128.f) - mean * mean;
      float rstd = rsqrtf(var + GN_EPS_F);
      size_t rowg = (size_t)(row0 + r) * Ndim + col0 + wn * 64;
#pragma unroll
      for (int n = 0; n < 4; ++n) {
        float v = (acc[m][n][i] - mean) * rstd * vgw[n] + vgb[n];
        out[rowg + n * 16 + lm] = v;
      }
    }
  }
}

extern "C" void kernel_launch(void* const* d_in, const int* in_sizes, int n_in,
                              void* d_out, int out_size, void* d_ws, size_t ws_size,
                              hipStream_t stream) {
  const float* x   = (const float*)d_in[0];
  const float* wgt = (const float*)d_in[1];
  const float* bl  = (const float*)d_in[2];
  const float* be  = (const float*)d_in[3];
  const float* gw  = (const float*)d_in[4];
  const float* gb  = (const float*)d_in[5];
  float* out = (float*)d_out;

  unsigned short* xbf = (unsigned short*)d_ws;                       // 64 MiB
  unsigned short* wbf = xbf + (size_t)Mdim * Kdim;                   // +32 MiB

  cvt_x<<<1024, 256, 0, stream>>>(x, xbf, Mdim * Kdim / 4);
  cvt_w<<<512, 256, 0, stream>>>(wgt, wbf, Ndim * Kdim / 4);

  int nwg = (Mdim / BM) * (Ndim / BN);  // 32*16 = 512
  fused_gemm_gn<<<nwg, 512, 0, stream>>>(xbf, wbf, bl, be, gw, gb, out);
}